// Round 1
// baseline (282.052 us; speedup 1.0000x reference)
//
#include <hip/hip_runtime.h>
#include <cstdint>
#include <cstddef>

#define BATCH 16
#define NCLS 80
#define NANCH 25200          // (80*80 + 40*40 + 20*20) * 3
#define G 48                 // anchors per chunk
#define NCHUNK 525           // chunks per image (400 + 100 + 25)
#define TOTCH (BATCH * NCHUNK)   // 8400
#define CPB 4                // chunks per k_max block
#define ABINS 512
#define SBINS 1024
#define SCAP 2048            // k_img LDS candidate cap (unchanged)
#define SCAP2 4096           // global per-image slist cap
#define KC 300
#define DET 100
#define SCORE_T 0.25f
#define NMS_T 0.45f
#define NBLK 50              // k_collect blocks per image
#define SPAN 504             // anchors per k_collect block (50*504 = 25200)

__device__ __forceinline__ float sg(float x) { return 1.0f / (1.0f + expf(-x)); }

__device__ __forceinline__ const float* anchor_base(const float* p3, const float* p4,
                                                    const float* p5, int b, int n) {
    if (n < 19200) return p3 + ((size_t)b * 19200 + n) * 85;
    if (n < 24000) return p4 + ((size_t)b * 4800 + (n - 19200)) * 85;
    return p5 + ((size_t)b * 1200 + (n - 24000)) * 85;
}

struct Chunk { const float4* p; int outbase; int b; };
__device__ __forceinline__ Chunk chunk_of(int g, const float* p3, const float* p4,
                                          const float* p5) {
    Chunk ck;
    int b = g / NCHUNK, ch = g % NCHUNK;
    const float* src; int a0, lvlN, gbase;
    if (ch < 400)      { src = p3; a0 = ch * G;         lvlN = 19200; gbase = 0; }
    else if (ch < 500) { src = p4; a0 = (ch - 400) * G; lvlN = 4800;  gbase = 19200; }
    else               { src = p5; a0 = (ch - 500) * G; lvlN = 1200;  gbase = 24000; }
    ck.p = (const float4*)(src + ((size_t)b * lvlN + a0) * 85);
    ck.outbase = b * NANCH + gbase + a0;
    ck.b = b;
    return ck;
}

// Streaming pass: per-anchor max score via sigma(obj)*sigma(max logit).
// NEW: also builds the per-image 512-bin anchor-max histogram (global atomics)
// so k_img no longer needs its two gmax passes + scan for Ta.
__global__ __launch_bounds__(256) void k_max(const float* __restrict__ p3,
                                             const float* __restrict__ p4,
                                             const float* __restrict__ p5,
                                             float* __restrict__ gmax,
                                             unsigned int* __restrict__ ahist) {
    __shared__ __align__(16) float buf[G * 85];   // 16320 B
    __shared__ float pmax[5 * G];
    int tid = threadIdx.x;
    int g0 = blockIdx.x * CPB;
    Chunk cur = chunk_of(g0, p3, p4, p5);
    float4 pre[4];
#pragma unroll
    for (int r = 0; r < 4; r++) {
        int i = tid + r * 256;
        pre[r] = (i < (G * 85 / 4)) ? cur.p[i] : make_float4(0.f, 0.f, 0.f, 0.f);
    }
    for (int it = 0; it < CPB; ++it) {
#pragma unroll
        for (int r = 0; r < 4; r++) {
            int i = tid + r * 256;
            if (i < (G * 85 / 4)) ((float4*)buf)[i] = pre[r];
        }
        Chunk nxt = cur;
        if (it + 1 < CPB) {
            nxt = chunk_of(g0 + it + 1, p3, p4, p5);
#pragma unroll
            for (int r = 0; r < 4; r++) {
                int i = tid + r * 256;
                pre[r] = (i < (G * 85 / 4)) ? nxt.p[i] : make_float4(0.f, 0.f, 0.f, 0.f);
            }
        }
        __syncthreads();
        if (tid < 240) {                   // 48 anchors x 5 parts of 16 classes
            int a = tid % G, part = tid / G;
            const float* base = buf + a * 85 + 5 + part * 16;
            float m = base[0];
#pragma unroll
            for (int k = 1; k < 16; k++) m = fmaxf(m, base[k]);
            pmax[part * G + a] = m;
        }
        __syncthreads();
        if (tid < G) {
            float m = pmax[tid];
#pragma unroll
            for (int p = 1; p < 5; p++) m = fmaxf(m, pmax[p * G + tid]);
            float obj = sg(buf[tid * 85 + 4]);
            float v = 0.0f;
            if (obj > SCORE_T) v = obj * sg(m);
            gmax[cur.outbase + tid] = v;
            if (v > SCORE_T) {
                int bin = (int)((v - SCORE_T) * (ABINS / 0.75f));
                bin = bin < 0 ? 0 : (bin > ABINS - 1 ? ABINS - 1 : bin);
                atomicAdd(&ahist[cur.b * ABINS + bin], 1u);
            }
        }
        __syncthreads();
        cur = nxt;
    }
}

// Parallel candidate scoring: 50 blocks/image. Each block redundantly derives Ta
// from the anchor histogram, filters its 504 anchors, computes each candidate
// score ONCE, and (prefiltered by the provable bound Ts >= 2*Ta) histograms it
// and appends (s, flat_idx) to the per-image global list.
__global__ __launch_bounds__(512) void k_collect(
    const float* __restrict__ p3, const float* __restrict__ p4, const float* __restrict__ p5,
    const float* __restrict__ gmax, const unsigned int* __restrict__ ahist,
    unsigned int* __restrict__ shist, unsigned int* __restrict__ scnt,
    float* __restrict__ ss, unsigned int* __restrict__ sidx) {
    __shared__ unsigned int h[ABINS];
    __shared__ int TaS;
    __shared__ int an[SPAN];
    __shared__ float og[SPAN];
    __shared__ unsigned int ncand;
    int tid = threadIdx.x;
    int b = blockIdx.x / NBLK;
    int blk = blockIdx.x % NBLK;
    if (tid == 0) { ncand = 0u; TaS = 0; }
    h[tid] = ahist[b * ABINS + tid];          // blockDim == ABINS
    __syncthreads();
    unsigned int run = h[tid];
    __syncthreads();
    for (int off = 1; off < ABINS; off <<= 1) {
        unsigned int add = (tid + off < ABINS) ? h[tid + off] : 0u;
        __syncthreads();
        run += add;
        h[tid] = run;
        __syncthreads();
    }
    if (run >= KC && (tid == ABINS - 1 || h[tid + 1] < KC)) TaS = tid;
    __syncthreads();
    int Ta = TaS;

    // filter this block's anchor span (bin >= Ta, identical bin expr as k_max)
    int n0 = blk * SPAN;
    for (int i = tid; i < SPAN; i += 512) {
        int n = n0 + i;
        float v = gmax[(size_t)b * NANCH + n];
        if (v > SCORE_T) {
            int bin = (int)((v - SCORE_T) * (ABINS / 0.75f));
            bin = bin < 0 ? 0 : (bin > ABINS - 1 ? ABINS - 1 : bin);
            if (bin >= Ta) {
                unsigned int p = atomicAdd(&ncand, 1u);
                an[p] = n;                    // p < SPAN always
            }
        }
    }
    __syncthreads();
    int M = (int)ncand;
    for (int i = tid; i < M; i += 512) {
        const float* pb = anchor_base(p3, p4, p5, b, an[i]);
        og[i] = sg(pb[4]);                    // same sg(obj) bits as the old tile path
    }
    __syncthreads();
    int twoTa = 2 * Ta;                       // provable: Ts >= 2*Ta
    for (int idx = tid; idx < M * NCLS; idx += 512) {
        int a = idx / NCLS, c = idx - a * NCLS;
        const float* pb = anchor_base(p3, p4, p5, b, an[a]);
        float s = og[a] * sg(pb[5 + c]);      // identical expression/order to before
        if (s > SCORE_T) {
            int bin = (int)((s - SCORE_T) * (SBINS / 0.75f));
            bin = bin < 0 ? 0 : (bin > SBINS - 1 ? SBINS - 1 : bin);
            if (bin >= twoTa) {
                atomicAdd(&shist[b * SBINS + bin], 1u);
                unsigned int p = atomicAdd(&scnt[b], 1u);
                if (p < SCAP2) {
                    ss[(size_t)b * SCAP2 + p] = s;
                    sidx[(size_t)b * SCAP2 + p] = (unsigned int)(an[a] * NCLS + c);
                }
            }
        }
    }
}

// NMS-phase LDS arrays (the staging tile overlay is gone — no staging here anymore).
struct NmsBuf {
    unsigned long long msk[KC * 5];                   // 12000 B
    float4 bx[KC];
    int lab[KC];
    float sc2[KC];
    float ar[KC];
    unsigned long long keep[5];
    unsigned int actw[10];
    int wpref[6];
    int order[DET];
    int okept[DET];
};

// Per-image kernel: Ts from prebuilt histogram, filter prebuilt candidate list,
// exact rank-select top-300, decode, NMS, output [100,6].
__global__ __launch_bounds__(1024) void k_img(
    const float* __restrict__ p3, const float* __restrict__ p4, const float* __restrict__ p5,
    const float* __restrict__ anchors, const int* __restrict__ imshapes,
    const float* __restrict__ scalef,
    const unsigned int* __restrict__ shist, const unsigned int* __restrict__ scnt_g,
    const float* __restrict__ ss, const unsigned int* __restrict__ sidx,
    float* __restrict__ out) {
    __shared__ unsigned int hist[SBINS];             // 4 KB
    __shared__ __align__(16) NmsBuf u;               // ~21.3 KB
    __shared__ float cs[SCAP];                       // 8 KB
    __shared__ unsigned int ci[SCAP];                // 8 KB
    __shared__ float sv[KC];
    __shared__ unsigned int si[KC];
    __shared__ unsigned int scnt_s;
    __shared__ int TsS;

    int b = blockIdx.x;
    int tid = threadIdx.x;
    if (tid == 0) { scnt_s = 0u; TsS = 0; }
    hist[tid] = shist[b * SBINS + tid];              // blockDim == SBINS
    __syncthreads();
    // suffix scan over 1024 bins (identical logic to before)
    unsigned int run = hist[tid];
    __syncthreads();
    for (int off = 1; off < SBINS; off <<= 1) {
        unsigned int add = (tid + off < SBINS) ? hist[tid + off] : 0u;
        __syncthreads();
        run += add;
        hist[tid] = run;
        __syncthreads();
    }
    if (run >= KC && (tid == SBINS - 1 || hist[tid + 1] < KC)) TsS = tid;
    __syncthreads();
    int Ts = TsS;

    // filter prebuilt list down to bin >= Ts (bin recomputed from identical float s)
    int navail = (int)(scnt_g[b] < SCAP2 ? scnt_g[b] : SCAP2);
    for (int i = tid; i < navail; i += 1024) {
        float s = ss[(size_t)b * SCAP2 + i];
        int bin = (int)((s - SCORE_T) * (SBINS / 0.75f));
        bin = bin < 0 ? 0 : (bin > SBINS - 1 ? SBINS - 1 : bin);
        if (bin >= Ts) {
            unsigned int pos = atomicAdd(&scnt_s, 1u);
            if (pos < SCAP) { cs[pos] = s; ci[pos] = sidx[(size_t)b * SCAP2 + i]; }
        }
    }
    __syncthreads();
    int nc = (int)(scnt_s < SCAP ? scnt_s : SCAP);

    // ---- F: rank-selection of top-300 (exact jax top_k order: score desc, idx asc) ----
    if (tid < KC) { sv[tid] = 0.f; si[tid] = 0xffffffffu; }
    __syncthreads();
    for (int i = tid; i < nc; i += 1024) {
        float s = cs[i];
        unsigned int ii = ci[i];
        int r = 0;
        for (int j = 0; j < nc; j++) {
            float sj = cs[j];
            unsigned int ij = ci[j];
            if (sj > s || (sj == s && ij < ii)) r++;
        }
        if (r < KC) { sv[r] = s; si[r] = ii; }
    }
    __syncthreads();
    int valid = nc < KC ? nc : KC;

    // ---- G: decode top-300 boxes ----
    if (tid < KC) {
        int i = tid;
        if (i < valid) {
            unsigned int fi = si[i];
            int n = (int)(fi / NCLS), c = (int)(fi % NCLS);
            int lvl = (n < 19200) ? 0 : (n < 24000 ? 1 : 2);
            const int offl[3] = {0, 19200, 24000};
            const int Wl[3] = {80, 40, 20};
            const int cntl[3] = {19200, 4800, 1200};
            const float strl[3] = {8.f, 16.f, 32.f};
            const float* pp = lvl == 0 ? p3 : (lvl == 1 ? p4 : p5);
            int nl = n - offl[lvl];
            int a = nl % 3, cell = nl / 3;
            int gx = cell % Wl[lvl], gy = cell / Wl[lvl];
            const float* pb = pp + ((size_t)b * cntl[lvl] + nl) * 85;
            float s0 = sg(pb[0]), s1 = sg(pb[1]), s2 = sg(pb[2]), s3 = sg(pb[3]);
            float stride = strl[lvl];
            float aw = anchors[(lvl * 3 + a) * 2 + 0];
            float ah = anchors[(lvl * 3 + a) * 2 + 1];
            float cx = (2.0f * s0 - 0.5f + (float)gx) * stride;
            float cy = (2.0f * s1 - 0.5f + (float)gy) * stride;
            float bw = 4.0f * s2 * s2 * aw;
            float bh = 4.0f * s3 * s3 * ah;
            float hf = (float)imshapes[b * 2 + 0];
            float wf = (float)imshapes[b * 2 + 1];
            float x1 = cx - bw / 2.0f, y1 = cy - bh / 2.0f;
            float x2 = cx + bw / 2.0f, y2 = cy + bh / 2.0f;
            x1 = fminf(fmaxf(x1, 0.f), wf);
            y1 = fminf(fmaxf(y1, 0.f), hf);
            x2 = fminf(fmaxf(x2, 0.f), wf);
            y2 = fminf(fmaxf(y2, 0.f), hf);
            u.bx[i] = make_float4(x1, y1, x2, y2);
            u.lab[i] = c;
            u.sc2[i] = sv[i];
            u.ar[i] = (x2 - x1) * (y2 - y1);
        } else {
            u.bx[i] = make_float4(0, 0, 0, 0);
            u.lab[i] = -1 - i;   // unique: never matches in NMS
            u.sc2[i] = 0.f;
            u.ar[i] = 0.f;
        }
    }
    __syncthreads();

    // ---- H: suppression bitmask rows ----
    if (tid < 10) u.actw[tid] = 0u;
    for (int t = tid; t < KC * 5; t += 1024) {
        int i = t / 5, w = t % 5;
        float4 bi = u.bx[i];
        int li = u.lab[i];
        float ai = u.ar[i];
        unsigned long long m = 0ull;
        for (int tb = 0; tb < 64; tb++) {
            int j = w * 64 + tb;
            if (j < KC && j > i && u.lab[j] == li) {
                float4 bj = u.bx[j];
                float ltx = fmaxf(bi.x, bj.x), lty = fmaxf(bi.y, bj.y);
                float rbx = fminf(bi.z, bj.z), rby = fminf(bi.w, bj.w);
                float iw = fmaxf(rbx - ltx, 0.f), ih = fmaxf(rby - lty, 0.f);
                float inter = iw * ih;
                float iou = inter / (ai + u.ar[j] - inter + 1e-9f);
                if (iou > NMS_T) m |= (1ull << tb);
            }
        }
        u.msk[t] = m;
    }
    __syncthreads();

    // ---- I: active-row NMS scan ----
    for (int i = tid; i < KC; i += 1024) {
        unsigned long long nz = u.msk[i * 5] | u.msk[i * 5 + 1] | u.msk[i * 5 + 2] |
                                u.msk[i * 5 + 3] | u.msk[i * 5 + 4];
        if (nz) atomicOr(&u.actw[i >> 5], 1u << (i & 31));
    }
    __syncthreads();
    if (tid == 0) {
        u.keep[0] = u.keep[1] = u.keep[2] = u.keep[3] = u.keep[4] = ~0ull;
        for (int w = 0; w < 10; w++) {
            unsigned int mw = u.actw[w];
            while (mw) {
                int bpos = __ffs(mw) - 1;
                mw &= mw - 1;
                int i = w * 32 + bpos;   // ascending i
                if ((u.keep[i >> 6] >> (i & 63)) & 1ull) {
#pragma unroll
                    for (int r = 0; r < 5; r++) u.keep[r] &= ~u.msk[i * 5 + r];
                }
            }
        }
        int s = 0;
        for (int w = 0; w < 5; w++) {
            unsigned long long kw = u.keep[w];
            if (w == 4) kw &= (1ull << 44) - 1ull;   // bits >= KC excluded
            u.wpref[w] = s;
            s += (int)__popcll(kw);
        }
        u.wpref[5] = s;
    }
    __syncthreads();

    // rank kept (index asc == score desc) then non-kept (index asc) via popcounts
    if (tid < KC) {
        int w = tid >> 6, bp = tid & 63;
        unsigned long long kw = u.keep[w];
        bool kept = (kw >> bp) & 1ull;
        int r = u.wpref[w] + (int)__popcll(kw & ((1ull << bp) - 1ull));
        if (kept) {
            if (r < DET) { u.order[r] = tid; u.okept[r] = 1; }
        } else {
            int nr = u.wpref[5] + (tid - r);
            if (nr < DET) { u.order[nr] = tid; u.okept[nr] = 0; }
        }
    }
    __syncthreads();

    if (tid < DET) {
        int o = u.order[tid];
        float scale = scalef[b];
        float4 bb = u.bx[o];
        float s = (u.okept[tid] && o < valid) ? u.sc2[o] : 0.f;
        float lb = (o < valid) ? (float)u.lab[o] : 0.f;
        float* po = out + ((size_t)b * DET + tid) * 6;
        po[0] = bb.x / scale;
        po[1] = bb.y / scale;
        po[2] = bb.z / scale;
        po[3] = bb.w / scale;
        po[4] = s;
        po[5] = lb;
    }
}

extern "C" void kernel_launch(void* const* d_in, const int* in_sizes, int n_in,
                              void* d_out, int out_size, void* d_ws, size_t ws_size,
                              hipStream_t stream) {
    const float* p3 = (const float*)d_in[0];
    const float* p4 = (const float*)d_in[1];
    const float* p5 = (const float*)d_in[2];
    const float* anchors = (const float*)d_in[3];
    const int* imshapes = (const int*)d_in[4];
    const float* scalef = (const float*)d_in[5];
    float* out = (float*)d_out;

    char* ws = (char*)d_ws;
    // layout: gmax | ahist | shist | scnt | ss | sidx
    float* gmax = (float*)ws;                                        // 16*25200*4 = 1,612,800 B
    unsigned int* ahist = (unsigned int*)(ws + 1612800);             // 16*512*4  =    32,768 B
    unsigned int* shist = (unsigned int*)(ws + 1612800 + 32768);     // 16*1024*4 =    65,536 B
    unsigned int* scnt  = (unsigned int*)(ws + 1612800 + 32768 + 65536);          //      64 B
    float* ss           = (float*)(ws + 1612800 + 32768 + 65536 + 64);            // 262,144 B
    unsigned int* sidx  = (unsigned int*)(ws + 1612800 + 32768 + 65536 + 64 + 262144); // 262,144 B

    // zero the accumulated regions (hists + counters); gmax is fully rewritten
    hipMemsetAsync(ws + 1612800, 0, 32768 + 65536 + 64, stream);

    k_max<<<TOTCH / CPB, 256, 0, stream>>>(p3, p4, p5, gmax, ahist);
    k_collect<<<BATCH * NBLK, 512, 0, stream>>>(p3, p4, p5, gmax, ahist, shist, scnt, ss, sidx);
    k_img<<<BATCH, 1024, 0, stream>>>(p3, p4, p5, anchors, imshapes, scalef,
                                      shist, scnt, ss, sidx, out);
}

// Round 3
// 227.423 us; speedup vs baseline: 1.2402x; 1.2402x over previous
//
#include <hip/hip_runtime.h>
#include <cstdint>
#include <cstddef>

#define BATCH 16
#define NCLS 80
#define NANCH 25200          // (80*80 + 40*40 + 20*20) * 3
#define G 48                 // anchors per chunk
#define NCHUNK 525           // chunks per image (400 + 100 + 25)
#define TOTCH (BATCH * NCHUNK)   // 8400
#define CPB 4                // chunks per k_max block
#define ABINS 512
#define SBINS 1024
#define SCAP 2048            // k_img LDS candidate cap
#define SCAP2 4096           // global per-image slist cap
#define LCAP 1024            // k_collect per-block LDS candidate cap
#define KC 300
#define DET 100
#define SCORE_T 0.25f
#define NMS_T 0.45f
#define NBLK 50              // k_collect blocks per image
#define SPAN 504             // anchors per k_collect block (50*504 = 25200)
#define CNTPAD 16            // scnt stride (dwords) -> one 64B line per image

__device__ __forceinline__ float sg(float x) { return 1.0f / (1.0f + expf(-x)); }

__device__ __forceinline__ const float* anchor_base(const float* p3, const float* p4,
                                                    const float* p5, int b, int n) {
    if (n < 19200) return p3 + ((size_t)b * 19200 + n) * 85;
    if (n < 24000) return p4 + ((size_t)b * 4800 + (n - 19200)) * 85;
    return p5 + ((size_t)b * 1200 + (n - 24000)) * 85;
}

struct Chunk { const float4* p; int outbase; int b; };
__device__ __forceinline__ Chunk chunk_of(int g, const float* p3, const float* p4,
                                          const float* p5) {
    Chunk ck;
    int b = g / NCHUNK, ch = g % NCHUNK;
    const float* src; int a0, lvlN, gbase;
    if (ch < 400)      { src = p3; a0 = ch * G;         lvlN = 19200; gbase = 0; }
    else if (ch < 500) { src = p4; a0 = (ch - 400) * G; lvlN = 4800;  gbase = 19200; }
    else               { src = p5; a0 = (ch - 500) * G; lvlN = 1200;  gbase = 24000; }
    ck.p = (const float4*)(src + ((size_t)b * lvlN + a0) * 85);
    ck.outbase = b * NANCH + gbase + a0;
    ck.b = b;
    return ck;
}

// Streaming pass: per-anchor max score via sigma(obj)*sigma(max logit).
// Also builds the per-image 512-bin anchor-max histogram (fire-and-forget atomics).
__global__ __launch_bounds__(256) void k_max(const float* __restrict__ p3,
                                             const float* __restrict__ p4,
                                             const float* __restrict__ p5,
                                             float* __restrict__ gmax,
                                             unsigned int* __restrict__ ahist) {
    __shared__ __align__(16) float buf[G * 85];   // 16320 B
    __shared__ float pmax[5 * G];
    int tid = threadIdx.x;
    int g0 = blockIdx.x * CPB;
    Chunk cur = chunk_of(g0, p3, p4, p5);
    float4 pre[4];
#pragma unroll
    for (int r = 0; r < 4; r++) {
        int i = tid + r * 256;
        pre[r] = (i < (G * 85 / 4)) ? cur.p[i] : make_float4(0.f, 0.f, 0.f, 0.f);
    }
    for (int it = 0; it < CPB; ++it) {
#pragma unroll
        for (int r = 0; r < 4; r++) {
            int i = tid + r * 256;
            if (i < (G * 85 / 4)) ((float4*)buf)[i] = pre[r];
        }
        Chunk nxt = cur;
        if (it + 1 < CPB) {
            nxt = chunk_of(g0 + it + 1, p3, p4, p5);
#pragma unroll
            for (int r = 0; r < 4; r++) {
                int i = tid + r * 256;
                pre[r] = (i < (G * 85 / 4)) ? nxt.p[i] : make_float4(0.f, 0.f, 0.f, 0.f);
            }
        }
        __syncthreads();
        if (tid < 240) {                   // 48 anchors x 5 parts of 16 classes
            int a = tid % G, part = tid / G;
            const float* base = buf + a * 85 + 5 + part * 16;
            float m = base[0];
#pragma unroll
            for (int k = 1; k < 16; k++) m = fmaxf(m, base[k]);
            pmax[part * G + a] = m;
        }
        __syncthreads();
        if (tid < G) {
            float m = pmax[tid];
#pragma unroll
            for (int p = 1; p < 5; p++) m = fmaxf(m, pmax[p * G + tid]);
            float obj = sg(buf[tid * 85 + 4]);
            float v = 0.0f;
            if (obj > SCORE_T) v = obj * sg(m);
            gmax[cur.outbase + tid] = v;
            if (v > SCORE_T) {
                int bin = (int)((v - SCORE_T) * (ABINS / 0.75f));
                bin = bin < 0 ? 0 : (bin > ABINS - 1 ? ABINS - 1 : bin);
                atomicAdd(&ahist[cur.b * ABINS + bin], 1u);   // result unused: fire-and-forget
            }
        }
        __syncthreads();
        cur = nxt;
    }
}

// Parallel candidate scoring. Candidates buffered in LDS; ONE range-reserving
// global atomic per block (on a per-image private cache line) instead of one
// result-carrying same-line atomic per candidate.
__global__ __launch_bounds__(512) void k_collect(
    const float* __restrict__ p3, const float* __restrict__ p4, const float* __restrict__ p5,
    const float* __restrict__ gmax, const unsigned int* __restrict__ ahist,
    unsigned int* __restrict__ shist, unsigned int* __restrict__ scnt,
    float* __restrict__ ss, unsigned int* __restrict__ sidx) {
    __shared__ unsigned int h[ABINS];
    __shared__ int TaS;
    __shared__ int an[SPAN];
    __shared__ float og[SPAN];
    __shared__ float lss[LCAP];
    __shared__ unsigned int lsi[LCAP];
    __shared__ unsigned int ncand, lcnt, gbase;
    int tid = threadIdx.x;
    int b = blockIdx.x / NBLK;
    int blk = blockIdx.x % NBLK;
    if (tid == 0) { ncand = 0u; TaS = 0; lcnt = 0u; }
    h[tid] = ahist[b * ABINS + tid];          // blockDim == ABINS
    __syncthreads();
    unsigned int run = h[tid];
    __syncthreads();
    for (int off = 1; off < ABINS; off <<= 1) {
        unsigned int add = (tid + off < ABINS) ? h[tid + off] : 0u;
        __syncthreads();
        run += add;
        h[tid] = run;
        __syncthreads();
    }
    if (run >= KC && (tid == ABINS - 1 || h[tid + 1] < KC)) TaS = tid;
    __syncthreads();
    int Ta = TaS;

    // filter this block's anchor span (bin >= Ta, identical bin expr as k_max)
    int n0 = blk * SPAN;
    for (int i = tid; i < SPAN; i += 512) {
        int n = n0 + i;
        float v = gmax[(size_t)b * NANCH + n];
        if (v > SCORE_T) {
            int bin = (int)((v - SCORE_T) * (ABINS / 0.75f));
            bin = bin < 0 ? 0 : (bin > ABINS - 1 ? ABINS - 1 : bin);
            if (bin >= Ta) {
                unsigned int p = atomicAdd(&ncand, 1u);
                an[p] = n;                    // p < SPAN always
            }
        }
    }
    __syncthreads();
    int M = (int)ncand;
    for (int i = tid; i < M; i += 512) {
        const float* pb = anchor_base(p3, p4, p5, b, an[i]);
        og[i] = sg(pb[4]);                    // same sg(obj) bits as before
    }
    __syncthreads();
    int twoTa = 2 * Ta;                       // provable: Ts >= 2*Ta
    for (int idx = tid; idx < M * NCLS; idx += 512) {
        int a = idx / NCLS, c = idx - a * NCLS;
        const float* pb = anchor_base(p3, p4, p5, b, an[a]);
        float s = og[a] * sg(pb[5 + c]);      // identical expression/order to before
        if (s > SCORE_T) {
            int bin = (int)((s - SCORE_T) * (SBINS / 0.75f));
            bin = bin < 0 ? 0 : (bin > SBINS - 1 ? SBINS - 1 : bin);
            if (bin >= twoTa) {
                atomicAdd(&shist[b * SBINS + bin], 1u);   // fire-and-forget, spread lines
                unsigned int p = atomicAdd(&lcnt, 1u);    // LDS atomic
                if (p < LCAP) {
                    lss[p] = s;
                    lsi[p] = (unsigned int)(an[a] * NCLS + c);
                } else {                                   // never in practice; safe fallback
                    unsigned int q = atomicAdd(&scnt[b * CNTPAD], 1u);
                    if (q < SCAP2) {
                        ss[(size_t)b * SCAP2 + q] = s;
                        sidx[(size_t)b * SCAP2 + q] = (unsigned int)(an[a] * NCLS + c);
                    }
                }
            }
        }
    }
    __syncthreads();
    unsigned int nl = lcnt < LCAP ? lcnt : LCAP;
    if (tid == 0 && nl > 0) gbase = atomicAdd(&scnt[b * CNTPAD], nl);
    __syncthreads();
    for (unsigned int i = tid; i < nl; i += 512) {
        unsigned int p = gbase + i;
        if (p < SCAP2) {
            ss[(size_t)b * SCAP2 + p] = lss[i];
            sidx[(size_t)b * SCAP2 + p] = lsi[i];
        }
    }
}

// NMS-phase LDS arrays.
struct NmsBuf {
    unsigned long long msk[KC * 5];                   // 12000 B
    float4 bx[KC];
    int lab[KC];
    float sc2[KC];
    float ar[KC];
    unsigned long long keep[5];
    unsigned int actw[10];
    int wpref[6];
    int order[DET];
    int okept[DET];
};

// Per-image kernel: Ts from prebuilt histogram (wave-shuffle suffix scan, 3 barriers),
// filter prebuilt candidate list, exact rank-select top-300, decode, NMS, output.
__global__ __launch_bounds__(1024) void k_img(
    const float* __restrict__ p3, const float* __restrict__ p4, const float* __restrict__ p5,
    const float* __restrict__ anchors, const int* __restrict__ imshapes,
    const float* __restrict__ scalef,
    const unsigned int* __restrict__ shist, const unsigned int* __restrict__ scnt_g,
    const float* __restrict__ ss, const unsigned int* __restrict__ sidx,
    float* __restrict__ out) {
    __shared__ unsigned int hist[SBINS];             // 4 KB
    __shared__ __align__(16) NmsBuf u;               // ~21.3 KB
    __shared__ float cs[SCAP];                       // 8 KB
    __shared__ unsigned int ci[SCAP];                // 8 KB
    __shared__ float sv[KC];
    __shared__ unsigned int si[KC];
    __shared__ unsigned int wtot[16], wsuf[16];
    __shared__ unsigned int scnt_s;
    __shared__ int TsS;

    int b = blockIdx.x;
    int tid = threadIdx.x;
    int lane = tid & 63, wv = tid >> 6;
    if (tid == 0) { scnt_s = 0u; TsS = 0; }

    // hierarchical suffix scan over 1024 bins: intra-wave shfl + 16-wave combine
    unsigned int run = shist[b * SBINS + tid];       // blockDim == SBINS
#pragma unroll
    for (int off = 1; off < 64; off <<= 1) {
        unsigned int v = __shfl_down(run, off, 64);
        if (lane + off < 64) run += v;
    }
    // lane l holds sum of bins [64*wv + l .. 64*wv + 63]; lane 0 = wave total
    if (lane == 0) wtot[wv] = run;
    __syncthreads();
    if (wv == 0) {                                   // all 64 lanes active for shfl
        unsigned int r = (lane < 16) ? wtot[lane] : 0u;
#pragma unroll
        for (int off = 1; off < 16; off <<= 1) {
            unsigned int v = __shfl_down(r, off, 64);
            if (lane + off < 16) r += v;
        }
        if (lane < 16) wsuf[lane] = r;               // suffix incl own wave
    }
    __syncthreads();
    unsigned int suf = run + ((wv < 15) ? wsuf[wv + 1] : 0u);   // = sum bins[tid..1023]
    hist[tid] = suf;
    __syncthreads();
    if (suf >= KC && (tid == SBINS - 1 || hist[tid + 1] < KC)) TsS = tid;
    __syncthreads();
    int Ts = TsS;

    // filter prebuilt list down to bin >= Ts (bin recomputed from identical float s)
    unsigned int total = scnt_g[b * CNTPAD];
    int navail = (int)(total < SCAP2 ? total : SCAP2);
    for (int i = tid; i < navail; i += 1024) {
        float s = ss[(size_t)b * SCAP2 + i];
        int bin = (int)((s - SCORE_T) * (SBINS / 0.75f));
        bin = bin < 0 ? 0 : (bin > SBINS - 1 ? SBINS - 1 : bin);
        if (bin >= Ts) {
            unsigned int pos = atomicAdd(&scnt_s, 1u);
            if (pos < SCAP) { cs[pos] = s; ci[pos] = sidx[(size_t)b * SCAP2 + i]; }
        }
    }
    __syncthreads();
    int nc = (int)(scnt_s < SCAP ? scnt_s : SCAP);

    // ---- F: rank-selection of top-300 (exact jax top_k order: score desc, idx asc) ----
    if (tid < KC) { sv[tid] = 0.f; si[tid] = 0xffffffffu; }
    __syncthreads();
    for (int i = tid; i < nc; i += 1024) {
        float s = cs[i];
        unsigned int ii = ci[i];
        int r = 0;
        for (int j = 0; j < nc; j++) {
            float sj = cs[j];
            unsigned int ij = ci[j];
            if (sj > s || (sj == s && ij < ii)) r++;
        }
        if (r < KC) { sv[r] = s; si[r] = ii; }
    }
    __syncthreads();
    int valid = nc < KC ? nc : KC;

    // ---- G: decode top-300 boxes ----
    if (tid < KC) {
        int i = tid;
        if (i < valid) {
            unsigned int fi = si[i];
            int n = (int)(fi / NCLS), c = (int)(fi % NCLS);
            int lvl = (n < 19200) ? 0 : (n < 24000 ? 1 : 2);
            const int offl[3] = {0, 19200, 24000};
            const int Wl[3] = {80, 40, 20};
            const int cntl[3] = {19200, 4800, 1200};
            const float strl[3] = {8.f, 16.f, 32.f};
            const float* pp = lvl == 0 ? p3 : (lvl == 1 ? p4 : p5);
            int nl = n - offl[lvl];
            int a = nl % 3, cell = nl / 3;
            int gx = cell % Wl[lvl], gy = cell / Wl[lvl];
            const float* pb = pp + ((size_t)b * cntl[lvl] + nl) * 85;
            float s0 = sg(pb[0]), s1 = sg(pb[1]), s2 = sg(pb[2]), s3 = sg(pb[3]);
            float stride = strl[lvl];
            float aw = anchors[(lvl * 3 + a) * 2 + 0];
            float ah = anchors[(lvl * 3 + a) * 2 + 1];
            float cx = (2.0f * s0 - 0.5f + (float)gx) * stride;
            float cy = (2.0f * s1 - 0.5f + (float)gy) * stride;
            float bw = 4.0f * s2 * s2 * aw;
            float bh = 4.0f * s3 * s3 * ah;
            float hf = (float)imshapes[b * 2 + 0];
            float wf = (float)imshapes[b * 2 + 1];
            float x1 = cx - bw / 2.0f, y1 = cy - bh / 2.0f;
            float x2 = cx + bw / 2.0f, y2 = cy + bh / 2.0f;
            x1 = fminf(fmaxf(x1, 0.f), wf);
            y1 = fminf(fmaxf(y1, 0.f), hf);
            x2 = fminf(fmaxf(x2, 0.f), wf);
            y2 = fminf(fmaxf(y2, 0.f), hf);
            u.bx[i] = make_float4(x1, y1, x2, y2);
            u.lab[i] = c;
            u.sc2[i] = sv[i];
            u.ar[i] = (x2 - x1) * (y2 - y1);
        } else {
            u.bx[i] = make_float4(0, 0, 0, 0);
            u.lab[i] = -1 - i;   // unique: never matches in NMS
            u.sc2[i] = 0.f;
            u.ar[i] = 0.f;
        }
    }
    __syncthreads();

    // ---- H: suppression bitmask rows ----
    if (tid < 10) u.actw[tid] = 0u;
    for (int t = tid; t < KC * 5; t += 1024) {
        int i = t / 5, w = t % 5;
        float4 bi = u.bx[i];
        int li = u.lab[i];
        float ai = u.ar[i];
        unsigned long long m = 0ull;
        for (int tb = 0; tb < 64; tb++) {
            int j = w * 64 + tb;
            if (j < KC && j > i && u.lab[j] == li) {
                float4 bj = u.bx[j];
                float ltx = fmaxf(bi.x, bj.x), lty = fmaxf(bi.y, bj.y);
                float rbx = fminf(bi.z, bj.z), rby = fminf(bi.w, bj.w);
                float iw = fmaxf(rbx - ltx, 0.f), ih = fmaxf(rby - lty, 0.f);
                float inter = iw * ih;
                float iou = inter / (ai + u.ar[j] - inter + 1e-9f);
                if (iou > NMS_T) m |= (1ull << tb);
            }
        }
        u.msk[t] = m;
    }
    __syncthreads();

    // ---- I: active-row NMS scan ----
    for (int i = tid; i < KC; i += 1024) {
        unsigned long long nz = u.msk[i * 5] | u.msk[i * 5 + 1] | u.msk[i * 5 + 2] |
                                u.msk[i * 5 + 3] | u.msk[i * 5 + 4];
        if (nz) atomicOr(&u.actw[i >> 5], 1u << (i & 31));
    }
    __syncthreads();
    if (tid == 0) {
        u.keep[0] = u.keep[1] = u.keep[2] = u.keep[3] = u.keep[4] = ~0ull;
        for (int w = 0; w < 10; w++) {
            unsigned int mw = u.actw[w];
            while (mw) {
                int bpos = __ffs(mw) - 1;
                mw &= mw - 1;
                int i = w * 32 + bpos;   // ascending i
                if ((u.keep[i >> 6] >> (i & 63)) & 1ull) {
#pragma unroll
                    for (int r = 0; r < 5; r++) u.keep[r] &= ~u.msk[i * 5 + r];
                }
            }
        }
        int s = 0;
        for (int w = 0; w < 5; w++) {
            unsigned long long kw = u.keep[w];
            if (w == 4) kw &= (1ull << 44) - 1ull;   // bits >= KC excluded
            u.wpref[w] = s;
            s += (int)__popcll(kw);
        }
        u.wpref[5] = s;
    }
    __syncthreads();

    // rank kept (index asc == score desc) then non-kept (index asc) via popcounts
    if (tid < KC) {
        int w = tid >> 6, bp = tid & 63;
        unsigned long long kw = u.keep[w];
        bool kept = (kw >> bp) & 1ull;
        int r = u.wpref[w] + (int)__popcll(kw & ((1ull << bp) - 1ull));
        if (kept) {
            if (r < DET) { u.order[r] = tid; u.okept[r] = 1; }
        } else {
            int nr = u.wpref[5] + (tid - r);
            if (nr < DET) { u.order[nr] = tid; u.okept[nr] = 0; }
        }
    }
    __syncthreads();

    if (tid < DET) {
        int o = u.order[tid];
        float scale = scalef[b];
        float4 bb = u.bx[o];
        float s = (u.okept[tid] && o < valid) ? u.sc2[o] : 0.f;
        float lb = (o < valid) ? (float)u.lab[o] : 0.f;
        float* po = out + ((size_t)b * DET + tid) * 6;
        po[0] = bb.x / scale;
        po[1] = bb.y / scale;
        po[2] = bb.z / scale;
        po[3] = bb.w / scale;
        po[4] = s;
        po[5] = lb;
    }
}

extern "C" void kernel_launch(void* const* d_in, const int* in_sizes, int n_in,
                              void* d_out, int out_size, void* d_ws, size_t ws_size,
                              hipStream_t stream) {
    const float* p3 = (const float*)d_in[0];
    const float* p4 = (const float*)d_in[1];
    const float* p5 = (const float*)d_in[2];
    const float* anchors = (const float*)d_in[3];
    const int* imshapes = (const int*)d_in[4];
    const float* scalef = (const float*)d_in[5];
    float* out = (float*)d_out;

    char* ws = (char*)d_ws;
    // layout: gmax | ahist | shist | scnt(padded) | ss | sidx
    float* gmax = (float*)ws;                                        // 16*25200*4 = 1,612,800 B
    unsigned int* ahist = (unsigned int*)(ws + 1612800);             // 16*512*4  =    32,768 B
    unsigned int* shist = (unsigned int*)(ws + 1612800 + 32768);     // 16*1024*4 =    65,536 B
    unsigned int* scnt  = (unsigned int*)(ws + 1612800 + 32768 + 65536);          //   1,024 B
    float* ss           = (float*)(ws + 1612800 + 32768 + 65536 + 1024);          // 262,144 B
    unsigned int* sidx  = (unsigned int*)(ws + 1612800 + 32768 + 65536 + 1024 + 262144); // 262,144 B

    // zero hists + counters; gmax is fully rewritten each launch
    hipMemsetAsync(ws + 1612800, 0, 32768 + 65536 + 1024, stream);

    k_max<<<TOTCH / CPB, 256, 0, stream>>>(p3, p4, p5, gmax, ahist);
    k_collect<<<BATCH * NBLK, 512, 0, stream>>>(p3, p4, p5, gmax, ahist, shist, scnt, ss, sidx);
    k_img<<<BATCH, 1024, 0, stream>>>(p3, p4, p5, anchors, imshapes, scalef,
                                      shist, scnt, ss, sidx, out);
}